// Round 13
// baseline (1042.089 us; speedup 1.0000x reference)
//
#include <hip/hip_runtime.h>
#include <math.h>
#include <stdint.h>

#define B_TOT 2048
#define SEQ   512
#define DIN   5
#define HID   64
#define EDIM  32
#define NEMB  64
#define BT    16
#define NBLK_STREAM 128
#define COMB  96
#define OUTC  (B_TOT*COMB)

typedef __attribute__((ext_vector_type(8))) _Float16 half8;  // 8 fp16 = 4 VGPRs
typedef __attribute__((ext_vector_type(4))) float float4v;

__device__ __forceinline__ float fsig(float x){ return 1.0f/(1.0f + __expf(-x)); }
__device__ __forceinline__ float ftanh(float x){
  float xc = fminf(fmaxf(x, -15.f), 15.f);
  float e  = __expf(-2.f*xc);
  return (1.f - e) / (1.f + e);
}
#define MFMA16(a,b,c) __builtin_amdgcn_mfma_f32_16x16x32_f16((a),(b),(c),0,0,0)
#define ZIDX(tile,k32,n) (((tile)*4 + (((k32)>>3)&3))*(BT*8) + (n)*8 + ((k32)&7))

// Fused dual-stream fp16, TWO-GROUP SOFTWARE PIPELINE. 256 blocks x 1024 thr
// (proven spill-free shape). blocks [0,128)=CNN, [128,256)=VQ. The 16 batch
// cols split: G0 = cols 0-7, G1 = cols 8-15, one shared Z buffer (5 K-tiles:
// T0=y/x, T1/2=h0, T3/4=h1). Phases alternate:
//   ODD : MFMA(G1,k)  + act(G0,k)  + stage G0 input(k+2)
//   EVEN: MFMA(G0,k+1)+ act(G1,k)  + stage G1 input(k+2)
// A phase's act consumes accumulator REGISTERS from the previous phase
// (cross-barrier HW interlock, no LDS wait) and its MFMA feeds the next
// phase -> no intra-phase dependency chain; LDS/MFMA/trans pipes overlap.
// Same-phase LDS writes touch only the other group's columns (disjoint
// words); the MFMA's other-group result columns are discarded.
// Act = 1 cell/lane/phase, BRANCHLESS: matching-half lanes (n16>>3 == group)
// do L1 with own accs; opposite lanes do L0 with shfl_xor(8) gates.
__global__ __launch_bounds__(1024)
__attribute__((amdgpu_waves_per_eu(4, 4)))
void fused_kernel(const float* __restrict__ xg,
                  const float* __restrict__ conv_w, const float* __restrict__ conv_b,
                  const float* __restrict__ bn_g, const float* __restrict__ bn_b,
                  const float* __restrict__ bn_m, const float* __restrict__ bn_v,
                  const float* __restrict__ cnn0_wih, const float* __restrict__ cnn0_whh,
                  const float* __restrict__ cnn0_bih, const float* __restrict__ cnn0_bhh,
                  const float* __restrict__ cnn1_wih, const float* __restrict__ cnn1_whh,
                  const float* __restrict__ cnn1_bih, const float* __restrict__ cnn1_bhh,
                  const float* __restrict__ vq0_wih, const float* __restrict__ vq0_whh,
                  const float* __restrict__ vq0_bih, const float* __restrict__ vq0_bhh,
                  const float* __restrict__ vq1_wih, const float* __restrict__ vq1_whh,
                  const float* __restrict__ vq1_bih, const float* __restrict__ vq1_bhh,
                  const float* __restrict__ proj_w, const float* __restrict__ proj_b,
                  const float* __restrict__ codebook,
                  float* __restrict__ out, float* __restrict__ ws_f,
                  int* __restrict__ ws_hist)
{
  __shared__ __align__(16) _Float16 ZT[5][4][BT][8];
  __shared__ __align__(16) float hfin[BT][HID];
  __shared__ __align__(16) float pbuf[BT][EDIM];
  __shared__ float wcs[16][32];
  __shared__ float xwin[4][BT][DIN];

  const int tid  = threadIdx.x;
  const bool is_cnn = (blockIdx.x < NBLK_STREAM);
  const int b0   = (is_cnn ? blockIdx.x : blockIdx.x - NBLK_STREAM) * BT;
  const int w    = tid >> 6;
  const int lane = tid & 63;
  const int n16  = lane & 15;     // batch col
  const int quad = lane >> 4;
  const int u    = 4*w + quad;    // unit owned by this lane
  const int half = n16 >> 3;      // 0: col in G0, 1: col in G1
  const int ocol = n16 ^ 8;       // partner column

  _Float16* Zb = (_Float16*)ZT;
  // act write addrs: in act_G0 lanes half0 write h1(T3/4,col n16), half1 write
  // h0(T1/2,col ocol); in act_G1 mirrored.
  const int wadrA = (half == 0) ? ZIDX(3 + (u>>5), u & 31, n16)
                                : ZIDX(1 + (u>>5), u & 31, ocol);
  const int wadrB = (half == 1) ? ZIDX(3 + (u>>5), u & 31, n16)
                                : ZIDX(1 + (u>>5), u & 31, ocol);

  const float* wih0 = is_cnn ? cnn0_wih : vq0_wih;
  const float* whh0 = is_cnn ? cnn0_whh : vq0_whh;
  const float* bih0 = is_cnn ? cnn0_bih : vq0_bih;
  const float* bhh0 = is_cnn ? cnn0_bhh : vq0_bhh;
  const float* wih1 = is_cnn ? cnn1_wih : vq1_wih;
  const float* whh1 = is_cnn ? cnn1_whh : vq1_whh;
  const float* bih1 = is_cnn ? cnn1_bih : vq1_bih;
  const float* bhh1 = is_cnn ? cnn1_bhh : vq1_bhh;

  // A-frags fp16, permuted rows (reg r = gate r of unit u). 28 VGPRs.
  const int orow = 64*(n16 & 3) + 4*w + (n16 >> 2);
  half8 Ah0[3], Ah1[4];
#pragma unroll
  for (int kt = 0; kt < 3; ++kt) {
    half8 vh;
#pragma unroll
    for (int j = 0; j < 8; ++j) {
      const int g = kt*32 + quad*8 + j;
      float wv;
      if (is_cnn) wv = (g < 32) ? wih0[orow*32 + g] : whh0[orow*64 + (g-32)];
      else        wv = (g < 5) ? wih0[orow*5 + g] : (g < 32 ? 0.f : whh0[orow*64 + (g-32)]);
      vh[j] = (_Float16)wv;
    }
    Ah0[kt] = vh;
  }
#pragma unroll
  for (int kt = 0; kt < 4; ++kt) {
    half8 vh;
#pragma unroll
    for (int j = 0; j < 8; ++j) {
      const int g = kt*32 + quad*8 + j;
      float wv = (g < 64) ? wih1[orow*64 + g] : whh1[orow*64 + (g-64)];
      vh[j] = (_Float16)wv;
    }
    Ah1[kt] = vh;
  }

  float4v bc0, bc1;
#pragma unroll
  for (int r = 0; r < 4; ++r) {
    bc0[r] = bih0[64*r + u] + bhh0[64*r + u];
    bc1[r] = bih1[64*r + u] + bhh1[64*r + u];
  }

  for (int i2 = tid; i2 < 5*4*BT*8/2; i2 += 1024) ((uint32_t*)ZT)[i2] = 0;

  const int xn = tid / 5, xi = tid % 5;
  float xpref = 0.f;                       // cnn: x(t+4) pipeline
  float xv0 = 0.f, xv1 = 0.f, xp = 0.f;    // vq per-col x pipeline

  if (is_cnn) {
    if (tid < 32) {
      float s = bn_g[tid] * rsqrtf(bn_v[tid] + 1e-5f);
#pragma unroll
      for (int i = 0; i < 5; ++i)
#pragma unroll
        for (int tau = 0; tau < 3; ++tau)
          wcs[tau*5 + i][tid] = conv_w[tid*15 + i*3 + tau] * s;
      wcs[15][tid] = (conv_b[tid] - bn_m[tid]) * s + bn_b[tid];
    }
    if (tid < 80) {
#pragma unroll
      for (int j = 0; j < 4; ++j)
        xwin[j][xn][xi] = xg[((size_t)(b0+xn)*SEQ + j)*DIN + xi];
      xpref = xg[((size_t)(b0+xn)*SEQ + 4)*DIN + xi];
    }
  } else {
    if (tid < 80) {
      xv0 = xg[((size_t)(b0+xn)*SEQ + 0)*DIN + xi];
      xv1 = xg[((size_t)(b0+xn)*SEQ + 1)*DIN + xi];
      xp  = xg[((size_t)(b0+xn)*SEQ + 2)*DIN + xi];
    }
  }
  __syncthreads();

  // stage T0 step-0 input, both groups
  if (is_cnn) {
    if (tid < 512) {
      const int cc = tid >> 4, cn = tid & 15;
      float s = wcs[15][cc];
#pragma unroll
      for (int i = 0; i < 5; ++i)
        s += wcs[5+i][cc]*xwin[0][cn][i] + wcs[10+i][cc]*xwin[1][cn][i];
      s = fmaxf(s, 0.f);
      Zb[ZIDX(0, cc, cn)] = (_Float16)s;
    }
  } else {
    if (tid < 80) Zb[ZIDX(0, xi, xn)] = (_Float16)xv0;
  }
  __syncthreads();

  float4v a1A, a0A, a1B, a0B;
  float cA = 0.f, cB = 0.f, h1v = 0.f;

  // phA: L0-only MFMA G0(0) (T1/T2 zero -> single T0 term)
  {
    half8 bt0 = *(const half8*)&ZT[0][quad][n16][0];
    a0A = MFMA16(Ah0[0], bt0, bc0);
  }
  __syncthreads();

  // phB: act L0-only G0(0) [half1 lanes] + stage G0 input(1) + L0-MFMA G1(0)
  {
    float s0 = __shfl_xor(a0A[0],8,64), s1 = __shfl_xor(a0A[1],8,64);
    float s2 = __shfl_xor(a0A[2],8,64), s3 = __shfl_xor(a0A[3],8,64);
    if (half == 1) {
      cA = fsig(s1)*cA + fsig(s0)*ftanh(s2);
      float h0 = fsig(s3)*ftanh(cA);
      Zb[wadrA] = (_Float16)h0;
    }
    if (is_cnn) {
      if (tid < 256) {
        const int cc = tid >> 3, cn = tid & 7;   // G0 col
        float s = wcs[15][cc];
#pragma unroll
        for (int i = 0; i < 5; ++i)
          s += wcs[i][cc]*xwin[0][cn][i] + wcs[5+i][cc]*xwin[1][cn][i]
             + wcs[10+i][cc]*xwin[2][cn][i];
        s = fmaxf(s, 0.f);
        Zb[ZIDX(0, cc, cn)] = (_Float16)s;
      }
    } else {
      if (tid < 80 && xn < 8) Zb[ZIDX(0, xi, xn)] = (_Float16)xv1;
    }
    half8 bt0 = *(const half8*)&ZT[0][quad][n16][0];  // G1 cols stable
    a0B = MFMA16(Ah0[0], bt0, bc0);
  }
  __syncthreads();

  // phC: act L0-only G1(0) [half0 lanes] + stage G1 input(1) + full MFMA G0(0)
  {
    float s0 = __shfl_xor(a0B[0],8,64), s1 = __shfl_xor(a0B[1],8,64);
    float s2 = __shfl_xor(a0B[2],8,64), s3 = __shfl_xor(a0B[3],8,64);
    if (half == 0) {
      cB = fsig(s1)*cB + fsig(s0)*ftanh(s2);
      float h0 = fsig(s3)*ftanh(cB);
      Zb[wadrB] = (_Float16)h0;
    }
    if (is_cnn) {
      if (tid < 256) {
        const int cc = tid >> 3, col = (tid & 7) + 8, cn = col;
        float s = wcs[15][cc];
#pragma unroll
        for (int i = 0; i < 5; ++i)
          s += wcs[i][cc]*xwin[0][cn][i] + wcs[5+i][cc]*xwin[1][cn][i]
             + wcs[10+i][cc]*xwin[2][cn][i];
        s = fmaxf(s, 0.f);
        Zb[ZIDX(0, cc, col)] = (_Float16)s;
      }
    } else {
      if (tid < 80 && xn >= 8) Zb[ZIDX(0, xi, xn)] = (_Float16)xv1;
    }
    half8 bt0 = *(const half8*)&ZT[0][quad][n16][0];
    half8 bt1 = *(const half8*)&ZT[1][quad][n16][0];
    half8 bt2 = *(const half8*)&ZT[2][quad][n16][0];
    a1A = MFMA16(Ah1[1], bt2, MFMA16(Ah1[0], bt1, bc1));   // T3/T4 zero
    a0A = MFMA16(Ah0[2], bt2, MFMA16(Ah0[1], bt1, MFMA16(Ah0[0], bt0, bc0)));
  }
  __syncthreads();

  // ================= main loop: 2 phases / step =================
  for (int k = 0; k < SEQ; ++k) {
    // ---- ODD: MFMA_G1(k) + act_G0(k) + stage G0(k+2)
    {
      half8 bt0 = *(const half8*)&ZT[0][quad][n16][0];
      half8 bt1 = *(const half8*)&ZT[1][quad][n16][0];
      half8 bt2 = *(const half8*)&ZT[2][quad][n16][0];
      half8 bt3 = *(const half8*)&ZT[3][quad][n16][0];
      half8 bt4 = *(const half8*)&ZT[4][quad][n16][0];
      float4v t1 = bc1, t0 = bc0;
      t1 = MFMA16(Ah1[0], bt1, t1); t1 = MFMA16(Ah1[1], bt2, t1);
      t1 = MFMA16(Ah1[2], bt3, t1); t1 = MFMA16(Ah1[3], bt4, t1);
      t0 = MFMA16(Ah0[0], bt0, t0); t0 = MFMA16(Ah0[1], bt1, t0);
      t0 = MFMA16(Ah0[2], bt2, t0);
      // act_G0(k): inputs = a1A,a0A (registers from previous phase)
      float s0 = __shfl_xor(a0A[0],8,64), s1 = __shfl_xor(a0A[1],8,64);
      float s2 = __shfl_xor(a0A[2],8,64), s3 = __shfl_xor(a0A[3],8,64);
      const bool mine = (half == 0);
      float g0 = mine ? a1A[0] : s0, g1 = mine ? a1A[1] : s1;
      float g2 = mine ? a1A[2] : s2, g3 = mine ? a1A[3] : s3;
      cA = fsig(g1)*cA + fsig(g0)*ftanh(g2);
      float h = fsig(g3)*ftanh(cA);
      Zb[wadrA] = (_Float16)h;
      if (mine) h1v = h;
      if (!is_cnn && k == SEQ-1 && mine) hfin[n16][u] = h;
      a1B = t1; a0B = t0;
      if (is_cnn) {
        if (tid < 256) {   // y_G0(k+2)
          const int cc = tid >> 3, cn = tid & 7;
          const int q1 = (k+1)&3, q2 = (k+2)&3, q3 = (k+3)&3;
          float s = wcs[15][cc];
#pragma unroll
          for (int i = 0; i < 5; ++i)
            s += wcs[i][cc]*xwin[q1][cn][i] + wcs[5+i][cc]*xwin[q2][cn][i]
               + wcs[10+i][cc]*xwin[q3][cn][i];
          s = fmaxf(s, 0.f);
          Zb[ZIDX(0, cc, cn)] = (_Float16)s;
        }
      } else {
        if (tid < 80 && xn < 8) {   // x_G0(k+2)
          Zb[ZIDX(0, xi, xn)] = (_Float16)xp;
          const int tq = k + 3;
          xp = (tq < SEQ) ? xg[((size_t)(b0+xn)*SEQ + tq)*DIN + xi] : 0.f;
        }
      }
    }
    __syncthreads();
    // ---- EVEN: MFMA_G0(k+1) [if any] + act_G1(k) + stage G1(k+2)
    {
      if (k < SEQ-1) {
        half8 bt0 = *(const half8*)&ZT[0][quad][n16][0];
        half8 bt1 = *(const half8*)&ZT[1][quad][n16][0];
        half8 bt2 = *(const half8*)&ZT[2][quad][n16][0];
        half8 bt3 = *(const half8*)&ZT[3][quad][n16][0];
        half8 bt4 = *(const half8*)&ZT[4][quad][n16][0];
        float4v t1 = bc1, t0 = bc0;
        t1 = MFMA16(Ah1[0], bt1, t1); t1 = MFMA16(Ah1[1], bt2, t1);
        t1 = MFMA16(Ah1[2], bt3, t1); t1 = MFMA16(Ah1[3], bt4, t1);
        t0 = MFMA16(Ah0[0], bt0, t0); t0 = MFMA16(Ah0[1], bt1, t0);
        t0 = MFMA16(Ah0[2], bt2, t0);
        a1A = t1; a0A = t0;
      }
      // act_G1(k): inputs = a1B,a0B
      float s0 = __shfl_xor(a0B[0],8,64), s1 = __shfl_xor(a0B[1],8,64);
      float s2 = __shfl_xor(a0B[2],8,64), s3 = __shfl_xor(a0B[3],8,64);
      const bool mine = (half == 1);
      float g0 = mine ? a1B[0] : s0, g1 = mine ? a1B[1] : s1;
      float g2 = mine ? a1B[2] : s2, g3 = mine ? a1B[3] : s3;
      cB = fsig(g1)*cB + fsig(g0)*ftanh(g2);
      float h = fsig(g3)*ftanh(cB);
      Zb[wadrB] = (_Float16)h;
      if (mine) h1v = h;
      if (!is_cnn && k == SEQ-1 && mine) hfin[n16][u] = h;
      if (is_cnn) {
        if (tid < 256) {   // y_G1(k+2)
          const int cc = tid >> 3, col = (tid & 7) + 8;
          const int q1 = (k+1)&3, q2 = (k+2)&3, q3 = (k+3)&3;
          float s = wcs[15][cc];
#pragma unroll
          for (int i = 0; i < 5; ++i)
            s += wcs[i][cc]*xwin[q1][col][i] + wcs[5+i][cc]*xwin[q2][col][i]
               + wcs[10+i][cc]*xwin[q3][col][i];
          s = fmaxf(s, 0.f);
          Zb[ZIDX(0, cc, col)] = (_Float16)s;
        }
        if (tid < 80) {    // commit x(k+4) -> dead slot, prefetch x(k+5)
          xwin[k & 3][xn][xi] = xpref;
          const int tq = k + 5;
          xpref = (tq < SEQ) ? xg[((size_t)(b0+xn)*SEQ + tq)*DIN + xi] : 0.f;
        }
      } else {
        if (tid < 80 && xn >= 8) {   // x_G1(k+2)
          Zb[ZIDX(0, xi, xn)] = (_Float16)xp;
          const int tq = k + 3;
          xp = (tq < SEQ) ? xg[((size_t)(b0+xn)*SEQ + tq)*DIN + xi] : 0.f;
        }
      }
    }
    __syncthreads();
  }

  // ================= epilogue =================
  if (is_cnn) {
    const size_t gb = (size_t)(b0 + n16);
    out[gb*COMB + u]        = h1v;
    out[OUTC + gb*COMB + u] = h1v;
  } else {
    if (tid < 512) {
      const int pn = tid >> 5, pe = tid & 31;
      float s = proj_b[pe];
      const float* pw = proj_w + pe*HID;
#pragma unroll
      for (int k = 0; k < HID; ++k) s += hfin[pn][k] * pw[k];
      pbuf[pn][pe] = s;
    }
    __syncthreads();
    {
      const int bb = w;
      const int nn = lane;
      const float* cbn = codebook + nn*EDIM;
      float d = 0.f;
#pragma unroll
      for (int k = 0; k < EDIM; ++k) { float df = pbuf[bb][k] - cbn[k]; d += df*df; }
      int bi = nn;
#pragma unroll
      for (int off = 32; off > 0; off >>= 1) {
        float od = __shfl_down(d, off, 64);
        int   oi = __shfl_down(bi, off, 64);
        if (od < d || (od == d && oi < bi)) { d = od; bi = oi; }
      }
      bi = __shfl(bi, 0, 64);
      float lv = 0.f;
      if (nn < EDIM) {
        float q = codebook[bi*EDIM + nn];
        const size_t gb = (size_t)(b0 + bb);
        out[gb*COMB + HID + nn]        = q;
        out[OUTC + gb*COMB + HID + nn] = q;
        float df = q - pbuf[bb][nn];
        lv = df*df;
      }
#pragma unroll
      for (int off = 32; off > 0; off >>= 1) lv += __shfl_down(lv, off, 64);
      if (nn == 0) { atomicAdd(ws_f, lv); atomicAdd(&ws_hist[bi], 1); }
    }
  }
}

// ===================== scalars =====================
__global__ void zero_ws_kernel(float* ws_f, int* ws_hist) {
  const int t = threadIdx.x;
  if (t == 0) ws_f[0] = 0.f;
  if (t < NEMB) ws_hist[t] = 0;
}

__global__ void vq_finalize_kernel(const float* __restrict__ ws_f,
                                   const int* __restrict__ ws_hist,
                                   float* __restrict__ out) {
  const int t = threadIdx.x;
  float p = (float)ws_hist[t] * (1.0f / (float)B_TOT);
  float e = -p * logf(p + 1e-10f);
#pragma unroll
  for (int off = 32; off > 0; off >>= 1) e += __shfl_down(e, off, 64);
  if (t == 0) {
    float mse = ws_f[0] * (1.0f / (float)(B_TOT * EDIM));
    out[2*OUTC + 0] = mse * 1.01f;
    out[2*OUTC + 1] = expf(e);
  }
}

extern "C" void kernel_launch(void* const* d_in, const int* in_sizes, int n_in,
                              void* d_out, int out_size, void* d_ws, size_t ws_size,
                              hipStream_t stream) {
  const float* x        = (const float*)d_in[0];
  const float* conv_w   = (const float*)d_in[1];
  const float* conv_b   = (const float*)d_in[2];
  const float* bn_g     = (const float*)d_in[3];
  const float* bn_b     = (const float*)d_in[4];
  const float* bn_m     = (const float*)d_in[5];
  const float* bn_v     = (const float*)d_in[6];
  const float* cnn0_wih = (const float*)d_in[7];
  const float* cnn0_whh = (const float*)d_in[8];
  const float* cnn0_bih = (const float*)d_in[9];
  const float* cnn0_bhh = (const float*)d_in[10];
  const float* cnn1_wih = (const float*)d_in[11];
  const float* cnn1_whh = (const float*)d_in[12];
  const float* cnn1_bih = (const float*)d_in[13];
  const float* cnn1_bhh = (const float*)d_in[14];
  const float* vq0_wih  = (const float*)d_in[15];
  const float* vq0_whh  = (const float*)d_in[16];
  const float* vq0_bih  = (const float*)d_in[17];
  const float* vq0_bhh  = (const float*)d_in[18];
  const float* vq1_wih  = (const float*)d_in[19];
  const float* vq1_whh  = (const float*)d_in[20];
  const float* vq1_bih  = (const float*)d_in[21];
  const float* vq1_bhh  = (const float*)d_in[22];
  const float* proj_w   = (const float*)d_in[23];
  const float* proj_b   = (const float*)d_in[24];
  const float* codebook = (const float*)d_in[25];

  float* out     = (float*)d_out;
  float* ws_f    = (float*)d_ws;
  int*   ws_hist = (int*)d_ws + 16;

  hipLaunchKernelGGL(zero_ws_kernel, dim3(1), dim3(64), 0, stream, ws_f, ws_hist);
  hipLaunchKernelGGL(fused_kernel, dim3(2*NBLK_STREAM), dim3(1024), 0, stream,
                     x, conv_w, conv_b, bn_g, bn_b, bn_m, bn_v,
                     cnn0_wih, cnn0_whh, cnn0_bih, cnn0_bhh,
                     cnn1_wih, cnn1_whh, cnn1_bih, cnn1_bhh,
                     vq0_wih, vq0_whh, vq0_bih, vq0_bhh,
                     vq1_wih, vq1_whh, vq1_bih, vq1_bhh,
                     proj_w, proj_b, codebook, out, ws_f, ws_hist);
  hipLaunchKernelGGL(vq_finalize_kernel, dim3(1), dim3(64), 0, stream, ws_f, ws_hist, out);
}